// Round 1
// baseline (415.380 us; speedup 1.0000x reference)
//
#include <hip/hip_runtime.h>
#include <hip/hip_bf16.h>

#define B_ROWS 16384
#define D_DIM  512
#define C_DIM  4096
#define H_DIM  1024

typedef __attribute__((ext_vector_type(8))) short  bf16x8;
typedef __attribute__((ext_vector_type(8))) unsigned short u16x8;
typedef __attribute__((ext_vector_type(4))) float  f32x4;

#define GLB __attribute__((address_space(1)))
#define LDS __attribute__((address_space(3)))

__device__ __forceinline__ unsigned short f2bf(float f) {
    unsigned int u = __float_as_uint(f);
    unsigned int r = (u + 0x7FFFu + ((u >> 16) & 1u)) >> 16;   // RNE
    return (unsigned short)r;
}

__device__ __forceinline__ void async16(const void* g, void* l) {
    __builtin_amdgcn_global_load_lds((const GLB unsigned int*)g,
                                     (LDS unsigned int*)l, 16, 0, 0);
}

__device__ __forceinline__ float read_sigma(const int* p) {
    int v = *p;
    if (v >= 1 && v < (1 << 20)) return (float)v;   // stored as int
    return __int_as_float(v);                        // stored as float bits
}

// ---- prep: convert one 512-col f32 row to bf16 + row sum of squares ----
__global__ __launch_bounds__(64) void prep_rows(const float* __restrict__ in,
                                                unsigned short* __restrict__ outb,
                                                float* __restrict__ out2) {
    int row  = blockIdx.x;
    int lane = threadIdx.x;
    const float4* p = (const float4*)(in + (size_t)row * D_DIM) + lane * 2;
    float4 a = p[0], b = p[1];
    float s = a.x*a.x + a.y*a.y + a.z*a.z + a.w*a.w
            + b.x*b.x + b.y*b.y + b.z*b.z + b.w*b.w;
    u16x8 o = { f2bf(a.x), f2bf(a.y), f2bf(a.z), f2bf(a.w),
                f2bf(b.x), f2bf(b.y), f2bf(b.z), f2bf(b.w) };
    *(u16x8*)(outb + (size_t)row * D_DIM + lane * 8) = o;
#pragma unroll
    for (int off = 32; off; off >>= 1) s += __shfl_down(s, off, 64);
    if (lane == 0) out2[row] = s;
}

// ---- prep: plain f32 -> bf16 convert (8 elems/thread) ----
__global__ __launch_bounds__(256) void conv_bf16(const float* __restrict__ in,
                                                 unsigned short* __restrict__ outb,
                                                 int n8) {
    int i = blockIdx.x * 256 + threadIdx.x;
    if (i >= n8) return;
    const float4* p = (const float4*)in + (size_t)i * 2;
    float4 a = p[0], b = p[1];
    u16x8 o = { f2bf(a.x), f2bf(a.y), f2bf(a.z), f2bf(a.w),
                f2bf(b.x), f2bf(b.y), f2bf(b.z), f2bf(b.w) };
    *((u16x8*)outb + i) = o;
}

// ---- stage a 128x64 bf16 tile: linear LDS dest, inverse-swizzled source ----
// read-side swizzle: chunk c (16B) of row r lives at LDS chunk (c ^ (r&7))
__device__ __forceinline__ void stage_tile(const unsigned short* __restrict__ g,
                                           int ld, int rowBase, int k0,
                                           unsigned short* lds, int tid) {
#pragma unroll
    for (int i = 0; i < 4; i++) {
        int idx = i * 256 + tid;          // 16B-chunk index, 0..1023
        int row = idx >> 3;               // 8 chunks per 64-elem row
        int cc  = (idx & 7) ^ (row & 7);  // inverse swizzle on SOURCE
        const unsigned short* src = g + (size_t)(rowBase + row) * ld + k0 + cc * 8;
        unsigned short* dst = lds + (size_t)(i * 256 + (tid & 192)) * 8; // wave-uniform base
        async16(src, dst);
    }
}

// ---- one BK=64 step of 4x4 16x16x32 MFMAs per wave ----
__device__ __forceinline__ void mma_k64(const unsigned short* As,
                                        const unsigned short* Bs,
                                        f32x4 (&acc)[4][4], int wr, int wc, int l) {
#pragma unroll
    for (int kk = 0; kk < 2; kk++) {
        int kc = kk * 4 + (l >> 4);
        bf16x8 a[4], b[4];
#pragma unroll
        for (int m = 0; m < 4; m++) {
            int r = wr + m * 16 + (l & 15);
            a[m] = *(const bf16x8*)(As + r * 64 + ((kc ^ (r & 7)) * 8));
        }
#pragma unroll
        for (int n = 0; n < 4; n++) {
            int r = wc + n * 16 + (l & 15);
            b[n] = *(const bf16x8*)(Bs + r * 64 + ((kc ^ (r & 7)) * 8));
        }
#pragma unroll
        for (int m = 0; m < 4; m++)
#pragma unroll
            for (int n = 0; n < 4; n++)
                acc[m][n] = __builtin_amdgcn_mfma_f32_16x16x32_bf16(a[m], b[n], acc[m][n], 0, 0, 0);
    }
}

// ---- GEMM1: xc = x @ centers^T ; epilogue -> phi bf16 ----
__global__ __launch_bounds__(256) void gemm1_kernel(const unsigned short* __restrict__ xb,
                                                    const unsigned short* __restrict__ cb,
                                                    const float* __restrict__ x2,
                                                    const float* __restrict__ c2,
                                                    const int* __restrict__ sigp,
                                                    unsigned short* __restrict__ phi) {
    __shared__ unsigned short As[128 * 64];
    __shared__ unsigned short Bs[128 * 64];
    int tid = threadIdx.x;
    int rowBase = blockIdx.y * 128;
    int colBase = blockIdx.x * 128;
    int l = tid & 63, w = tid >> 6;
    int wr = (w >> 1) * 64, wc = (w & 1) * 64;

    f32x4 acc[4][4] = {};
    for (int k0 = 0; k0 < D_DIM; k0 += 64) {
        stage_tile(xb, D_DIM, rowBase, k0, As, tid);
        stage_tile(cb, D_DIM, colBase, k0, Bs, tid);
        __syncthreads();
        mma_k64(As, Bs, acc, wr, wc, l);
        __syncthreads();
    }

    float inv2s = 0.5f / read_sigma(sigp);
    int r0 = rowBase + wr + (l >> 4) * 4;
    int c0 = colBase + wc + (l & 15);
#pragma unroll
    for (int m = 0; m < 4; m++) {
#pragma unroll
        for (int j = 0; j < 4; j++) {
            int row = r0 + m * 16 + j;
            float xr = x2[row];
#pragma unroll
            for (int n = 0; n < 4; n++) {
                int col = c0 + n * 16;
                float d2 = xr + c2[col] - 2.0f * acc[m][n][j];
                d2 = fmaxf(d2, 0.0f);
                float ph = __expf(-__builtin_sqrtf(d2) * inv2s);
                phi[(size_t)row * C_DIM + col] = f2bf(ph);
            }
        }
    }
}

// ---- GEMM2: out = sigmoid(phi @ W1^T + b1) ----
__global__ __launch_bounds__(256) void gemm2_kernel(const unsigned short* __restrict__ phi,
                                                    const unsigned short* __restrict__ wb,
                                                    const float* __restrict__ b1,
                                                    float* __restrict__ out) {
    __shared__ unsigned short As[128 * 64];
    __shared__ unsigned short Bs[128 * 64];
    int tid = threadIdx.x;
    int rowBase = blockIdx.y * 128;
    int colBase = blockIdx.x * 128;
    int l = tid & 63, w = tid >> 6;
    int wr = (w >> 1) * 64, wc = (w & 1) * 64;

    f32x4 acc[4][4] = {};
    for (int k0 = 0; k0 < C_DIM; k0 += 64) {
        stage_tile(phi, C_DIM, rowBase, k0, As, tid);
        stage_tile(wb, C_DIM, colBase, k0, Bs, tid);
        __syncthreads();
        mma_k64(As, Bs, acc, wr, wc, l);
        __syncthreads();
    }

    int r0 = rowBase + wr + (l >> 4) * 4;
    int c0 = colBase + wc + (l & 15);
#pragma unroll
    for (int m = 0; m < 4; m++) {
#pragma unroll
        for (int j = 0; j < 4; j++) {
            int row = r0 + m * 16 + j;
#pragma unroll
            for (int n = 0; n < 4; n++) {
                int col = c0 + n * 16;
                float z = acc[m][n][j] + b1[col];
                out[(size_t)row * H_DIM + col] = 1.0f / (1.0f + __expf(-z));
            }
        }
    }
}

extern "C" void kernel_launch(void* const* d_in, const int* in_sizes, int n_in,
                              void* d_out, int out_size, void* d_ws, size_t ws_size,
                              hipStream_t stream) {
    const float* x       = (const float*)d_in[0];
    const float* centers = (const float*)d_in[1];
    const float* W1      = (const float*)d_in[2];
    const float* b1      = (const float*)d_in[3];
    const int*   sig     = (const int*)d_in[4];
    float* out = (float*)d_out;

    char* ws = (char*)d_ws;
    unsigned short* phi = (unsigned short*)(ws);                 // 16384*4096*2 = 134217728
    unsigned short* xb  = (unsigned short*)(ws + 134217728);     // 16384*512*2  = 16777216
    unsigned short* cb  = (unsigned short*)(ws + 150994944);     // 4096*512*2   = 4194304
    unsigned short* wb  = (unsigned short*)(ws + 155189248);     // 1024*4096*2  = 8388608
    float* x2 = (float*)(ws + 163577856);                        // 16384*4
    float* c2 = (float*)(ws + 163643392);                        // 4096*4

    prep_rows<<<B_ROWS, 64, 0, stream>>>(x, xb, x2);
    prep_rows<<<C_DIM, 64, 0, stream>>>(centers, cb, c2);
    conv_bf16<<<(H_DIM * C_DIM / 8 + 255) / 256, 256, 0, stream>>>(W1, wb, H_DIM * C_DIM / 8);

    gemm1_kernel<<<dim3(C_DIM / 128, B_ROWS / 128), 256, 0, stream>>>(xb, cb, x2, c2, sig, phi);
    gemm2_kernel<<<dim3(H_DIM / 128, B_ROWS / 128), 256, 0, stream>>>(phi, wb, b1, out);
}

// Round 4
// 341.243 us; speedup vs baseline: 1.2173x; 1.2173x over previous
//
#include <hip/hip_runtime.h>
#include <hip/hip_bf16.h>

#define B_ROWS 16384
#define D_DIM  512
#define C_DIM  4096
#define H_DIM  1024

typedef __attribute__((ext_vector_type(8))) short  bf16x8;
typedef __attribute__((ext_vector_type(8))) unsigned short u16x8;
typedef __attribute__((ext_vector_type(4))) float  f32x4;

#define GLB __attribute__((address_space(1)))
#define LDS __attribute__((address_space(3)))

#define MFMA(d, va, vb) d = __builtin_amdgcn_mfma_f32_16x16x32_bf16(va, vb, d, 0, 0, 0)

__device__ __forceinline__ unsigned short f2bf(float f) {
    unsigned int u = __float_as_uint(f);
    unsigned int r = (u + 0x7FFFu + ((u >> 16) & 1u)) >> 16;   // RNE
    return (unsigned short)r;
}

__device__ __forceinline__ void async16(const void* g, void* l) {
    __builtin_amdgcn_global_load_lds((const GLB unsigned int*)g,
                                     (LDS unsigned int*)l, 16, 0, 0);
}

__device__ __forceinline__ float read_sigma(const int* p) {
    int v = *p;
    if (v >= 1 && v < (1 << 20)) return (float)v;   // stored as int
    return __int_as_float(v);                        // stored as float bits
}

// ---- prep: convert one 512-col f32 row to bf16 + row sum of squares ----
__global__ __launch_bounds__(64) void prep_rows(const float* __restrict__ in,
                                                unsigned short* __restrict__ outb,
                                                float* __restrict__ out2) {
    int row  = blockIdx.x;
    int lane = threadIdx.x;
    const float4* p = (const float4*)(in + (size_t)row * D_DIM) + lane * 2;
    float4 a = p[0], b = p[1];
    float s = a.x*a.x + a.y*a.y + a.z*a.z + a.w*a.w
            + b.x*b.x + b.y*b.y + b.z*b.z + b.w*b.w;
    u16x8 o = { f2bf(a.x), f2bf(a.y), f2bf(a.z), f2bf(a.w),
                f2bf(b.x), f2bf(b.y), f2bf(b.z), f2bf(b.w) };
    *(u16x8*)(outb + (size_t)row * D_DIM + lane * 8) = o;
#pragma unroll
    for (int off = 32; off; off >>= 1) s += __shfl_down(s, off, 64);
    if (lane == 0) out2[row] = s;
}

// ---- prep: plain f32 -> bf16 convert (8 elems/thread) ----
__global__ __launch_bounds__(256) void conv_bf16(const float* __restrict__ in,
                                                 unsigned short* __restrict__ outb,
                                                 int n8) {
    int i = blockIdx.x * 256 + threadIdx.x;
    if (i >= n8) return;
    const float4* p = (const float4*)in + (size_t)i * 2;
    float4 a = p[0], b = p[1];
    u16x8 o = { f2bf(a.x), f2bf(a.y), f2bf(a.z), f2bf(a.w),
                f2bf(b.x), f2bf(b.y), f2bf(b.z), f2bf(b.w) };
    *((u16x8*)outb + i) = o;
}

// ---- stage a 128x64 bf16 half-tile (512 threads, 2 gload_lds each) ----
// linear LDS dest; inverse swizzle on SOURCE; read-side chunk swizzle c^(r&7)
__device__ __forceinline__ void stage_half(const unsigned short* __restrict__ g,
                                           int ld, int rowBase, int k0,
                                           unsigned short* lds, int tid) {
#pragma unroll
    for (int i = 0; i < 2; i++) {
        int idx = i * 512 + tid;          // 16B-chunk index, 0..1023
        int row = idx >> 3;               // 8 chunks per 64-elem row
        int cc  = (idx & 7) ^ (row & 7);  // inverse swizzle on SOURCE
        const unsigned short* src = g + (size_t)(rowBase + row) * ld + k0 + cc * 8;
        unsigned short* dst = lds + (i * 512 + (tid & 448)) * 8; // wave-uniform base
        async16(src, dst);
    }
}

__device__ __forceinline__ bf16x8 frag(const unsigned short* T, int r, int kc) {
    return *(const bf16x8*)(T + r * 64 + ((kc ^ (r & 7)) << 3));
}

// ---- one K-tile (BK=64): 4 phases, 16 MFMA each; stages K-tile t+2 ----
__device__ __forceinline__ void ktile(unsigned short* __restrict__ Ap,
                                      unsigned short* __restrict__ Bp,
                                      const unsigned short* __restrict__ gA, int lda, int aRow0,
                                      const unsigned short* __restrict__ gB, int ldb, int bRow0,
                                      int kNext, bool doStage,
                                      f32x4 (&acc)[8][4], int tid, int l, int AR, int BC) {
    const int lr = l & 15, hi = l >> 4;
    bf16x8 a[4][2], b0[2][2], b1[2][2];

    // ---- PH0: ds_read A m0-3 + B n0-1 (12 reads); MFMA m0-3 x n0-1 ----
#pragma unroll
    for (int m = 0; m < 4; m++) { int r = AR + m * 16 + lr;
#pragma unroll
        for (int kk = 0; kk < 2; kk++) a[m][kk] = frag(Ap, r, kk * 4 + hi); }
#pragma unroll
    for (int n = 0; n < 2; n++) { int r = BC + n * 16 + lr;
#pragma unroll
        for (int kk = 0; kk < 2; kk++) b0[n][kk] = frag(Bp, r, kk * 4 + hi); }
    __builtin_amdgcn_s_barrier();
    __builtin_amdgcn_s_setprio(1);
#pragma unroll
    for (int m = 0; m < 4; m++)
#pragma unroll
        for (int n = 0; n < 2; n++)
#pragma unroll
            for (int kk = 0; kk < 2; kk++) MFMA(acc[m][n], a[m][kk], b0[n][kk]);
    __builtin_amdgcn_s_setprio(0);
    __builtin_amdgcn_s_barrier();

    // ---- PH1: ds_read B n2-3 (4 reads); MFMA m0-3 x n2-3 ----
#pragma unroll
    for (int n = 0; n < 2; n++) { int r = BC + (n + 2) * 16 + lr;
#pragma unroll
        for (int kk = 0; kk < 2; kk++) b1[n][kk] = frag(Bp, r, kk * 4 + hi); }
    __builtin_amdgcn_s_barrier();
    __builtin_amdgcn_s_setprio(1);
#pragma unroll
    for (int m = 0; m < 4; m++)
#pragma unroll
        for (int n = 0; n < 2; n++)
#pragma unroll
            for (int kk = 0; kk < 2; kk++) MFMA(acc[m][2 + n], a[m][kk], b1[n][kk]);
    __builtin_amdgcn_s_setprio(0);
    __builtin_amdgcn_s_barrier();

    // ---- PH2: ds_read A m4-7 (8 reads); stage B halves of t+2; MFMA m4-7 x n0-1 ----
#pragma unroll
    for (int m = 0; m < 4; m++) { int r = AR + (m + 4) * 16 + lr;
#pragma unroll
        for (int kk = 0; kk < 2; kk++) a[m][kk] = frag(Ap, r, kk * 4 + hi); }
    if (doStage) {
        stage_half(gB, ldb, bRow0,       kNext, Bp,        tid);
        stage_half(gB, ldb, bRow0 + 128, kNext, Bp + 8192, tid);
    }
    __builtin_amdgcn_s_barrier();
    __builtin_amdgcn_s_setprio(1);
#pragma unroll
    for (int m = 0; m < 4; m++)
#pragma unroll
        for (int n = 0; n < 2; n++)
#pragma unroll
            for (int kk = 0; kk < 2; kk++) MFMA(acc[4 + m][n], a[m][kk], b0[n][kk]);
    __builtin_amdgcn_s_setprio(0);
    __builtin_amdgcn_s_barrier();

    // ---- PH3: stage A halves of t+2; MFMA m4-7 x n2-3; boundary vmcnt(8) ----
    if (doStage) {
        stage_half(gA, lda, aRow0,       kNext, Ap,        tid);
        stage_half(gA, lda, aRow0 + 128, kNext, Ap + 8192, tid);
    }
    __builtin_amdgcn_s_barrier();
    __builtin_amdgcn_s_setprio(1);
#pragma unroll
    for (int m = 0; m < 4; m++)
#pragma unroll
        for (int n = 0; n < 2; n++)
#pragma unroll
            for (int kk = 0; kk < 2; kk++) MFMA(acc[4 + m][2 + n], a[m][kk], b1[n][kk]);
    __builtin_amdgcn_s_setprio(0);
    asm volatile("s_waitcnt vmcnt(8)" ::: "memory");   // keep t+2's 8 loads in flight
    __builtin_amdgcn_s_barrier();
}

__device__ __forceinline__ void gemm_core(const unsigned short* __restrict__ gA, int lda, int aRow0,
                                          const unsigned short* __restrict__ gB, int ldb, int bRow0,
                                          int nt, f32x4 (&acc)[8][4],
                                          unsigned short (&As)[2][16384],
                                          unsigned short (&Bs)[2][16384],
                                          int tid, int l, int AR, int BC) {
    // prologue: stage K-tiles 0 and 1 (order matters for vmcnt aging)
    stage_half(gA, lda, aRow0,       0,  As[0],        tid);
    stage_half(gA, lda, aRow0 + 128, 0,  As[0] + 8192, tid);
    stage_half(gB, ldb, bRow0,       0,  Bs[0],        tid);
    stage_half(gB, ldb, bRow0 + 128, 0,  Bs[0] + 8192, tid);
    stage_half(gA, lda, aRow0,       64, As[1],        tid);
    stage_half(gA, lda, aRow0 + 128, 64, As[1] + 8192, tid);
    stage_half(gB, ldb, bRow0,       64, Bs[1],        tid);
    stage_half(gB, ldb, bRow0 + 128, 64, Bs[1] + 8192, tid);
    asm volatile("s_waitcnt vmcnt(8)" ::: "memory");   // tile0 landed; tile1 in flight
    __builtin_amdgcn_s_barrier();

    for (int t = 0; t < nt; t += 2) {
        ktile(As[0], Bs[0], gA, lda, aRow0, gB, ldb, bRow0, (t + 2) * 64, t + 2 < nt,
              acc, tid, l, AR, BC);
        ktile(As[1], Bs[1], gA, lda, aRow0, gB, ldb, bRow0, (t + 3) * 64, t + 3 < nt,
              acc, tid, l, AR, BC);
    }
}

// ---- GEMM1: xc = x @ centers^T ; epilogue -> phi bf16 ----
__global__ __launch_bounds__(512) void gemm1_kernel(const unsigned short* __restrict__ xb,
                                                    const unsigned short* __restrict__ cb,
                                                    const float* __restrict__ x2,
                                                    const float* __restrict__ c2,
                                                    const int* __restrict__ sigp,
                                                    unsigned short* __restrict__ phi) {
    __shared__ unsigned short As[2][16384];
    __shared__ unsigned short Bs[2][16384];
    int tid = threadIdx.x;
    // XCD-chunked swizzle (nwg = 1024, %8 == 0)
    int nwg = gridDim.x, cpx = nwg >> 3, bid = blockIdx.x;
    int nb = (bid & 7) * cpx + (bid >> 3);
    const int nbx = C_DIM / 256;
    int aRow0 = (nb / nbx) * 256, bRow0 = (nb % nbx) * 256;
    int l = tid & 63, wid = tid >> 6;
    int AR = (wid >> 2) * 128, BC = (wid & 3) * 64;

    f32x4 acc[8][4] = {};
    gemm_core(xb, D_DIM, aRow0, cb, D_DIM, bRow0, D_DIM / 64, acc, As, Bs, tid, l, AR, BC);

    float inv2s = 0.5f / read_sigma(sigp);
    int lr = l & 15, hi = l >> 4;
#pragma unroll
    for (int m = 0; m < 8; m++) {
#pragma unroll
        for (int j = 0; j < 4; j++) {
            int row = aRow0 + AR + m * 16 + hi * 4 + j;
            float xr = x2[row];
#pragma unroll
            for (int n = 0; n < 4; n++) {
                int col = bRow0 + BC + n * 16 + lr;
                float d2 = fmaxf(xr + c2[col] - 2.0f * acc[m][n][j], 0.0f);
                float ph = __expf(-__builtin_sqrtf(d2) * inv2s);
                phi[(size_t)row * C_DIM + col] = f2bf(ph);
            }
        }
    }
}

// ---- GEMM2: out = sigmoid(phi @ W1^T + b1) ----
__global__ __launch_bounds__(512) void gemm2_kernel(const unsigned short* __restrict__ phi,
                                                    const unsigned short* __restrict__ wb,
                                                    const float* __restrict__ b1,
                                                    float* __restrict__ out) {
    __shared__ unsigned short As[2][16384];
    __shared__ unsigned short Bs[2][16384];
    int tid = threadIdx.x;
    // XCD-chunked swizzle (nwg = 256, %8 == 0)
    int nwg = gridDim.x, cpx = nwg >> 3, bid = blockIdx.x;
    int nb = (bid & 7) * cpx + (bid >> 3);
    const int nbx = H_DIM / 256;
    int aRow0 = (nb / nbx) * 256, bRow0 = (nb % nbx) * 256;
    int l = tid & 63, wid = tid >> 6;
    int AR = (wid >> 2) * 128, BC = (wid & 3) * 64;

    f32x4 acc[8][4] = {};
    gemm_core(phi, C_DIM, aRow0, wb, C_DIM, bRow0, C_DIM / 64, acc, As, Bs, tid, l, AR, BC);

    int lr = l & 15, hi = l >> 4;
#pragma unroll
    for (int m = 0; m < 8; m++) {
#pragma unroll
        for (int j = 0; j < 4; j++) {
            int row = aRow0 + AR + m * 16 + hi * 4 + j;
#pragma unroll
            for (int n = 0; n < 4; n++) {
                int col = bRow0 + BC + n * 16 + lr;
                float z = acc[m][n][j] + b1[col];
                out[(size_t)row * H_DIM + col] = 1.0f / (1.0f + __expf(-z));
            }
        }
    }
}

extern "C" void kernel_launch(void* const* d_in, const int* in_sizes, int n_in,
                              void* d_out, int out_size, void* d_ws, size_t ws_size,
                              hipStream_t stream) {
    const float* x       = (const float*)d_in[0];
    const float* centers = (const float*)d_in[1];
    const float* W1      = (const float*)d_in[2];
    const float* b1      = (const float*)d_in[3];
    const int*   sig     = (const int*)d_in[4];
    float* out = (float*)d_out;

    char* ws = (char*)d_ws;
    unsigned short* phi = (unsigned short*)(ws);                 // 16384*4096*2 = 134217728
    unsigned short* xb  = (unsigned short*)(ws + 134217728);     // 16384*512*2  = 16777216
    unsigned short* cb  = (unsigned short*)(ws + 150994944);     // 4096*512*2   = 4194304
    unsigned short* wb  = (unsigned short*)(ws + 155189248);     // 1024*4096*2  = 8388608
    float* x2 = (float*)(ws + 163577856);                        // 16384*4
    float* c2 = (float*)(ws + 163643392);                        // 4096*4

    prep_rows<<<B_ROWS, 64, 0, stream>>>(x, xb, x2);
    prep_rows<<<C_DIM, 64, 0, stream>>>(centers, cb, c2);
    conv_bf16<<<(H_DIM * C_DIM / 8 + 255) / 256, 256, 0, stream>>>(W1, wb, H_DIM * C_DIM / 8);

    gemm1_kernel<<<(B_ROWS / 256) * (C_DIM / 256), 512, 0, stream>>>(xb, cb, x2, c2, sig, phi);
    gemm2_kernel<<<(B_ROWS / 256) * (H_DIM / 256), 512, 0, stream>>>(phi, wb, b1, out);
}

// Round 5
// 337.220 us; speedup vs baseline: 1.2318x; 1.0119x over previous
//
#include <hip/hip_runtime.h>
#include <hip/hip_bf16.h>

#define B_ROWS 16384
#define D_DIM  512
#define C_DIM  4096
#define H_DIM  1024

typedef __attribute__((ext_vector_type(8))) short  bf16x8;
typedef __attribute__((ext_vector_type(8))) unsigned short u16x8;
typedef __attribute__((ext_vector_type(4))) float  f32x4;

#define GLB __attribute__((address_space(1)))
#define LDS __attribute__((address_space(3)))

#define MFMA(d, va, vb) d = __builtin_amdgcn_mfma_f32_16x16x32_bf16(va, vb, d, 0, 0, 0)
#define LGKM0() asm volatile("s_waitcnt lgkmcnt(0)" ::: "memory")

__device__ __forceinline__ unsigned short f2bf(float f) {
    unsigned int u = __float_as_uint(f);
    unsigned int r = (u + 0x7FFFu + ((u >> 16) & 1u)) >> 16;   // RNE
    return (unsigned short)r;
}

__device__ __forceinline__ void async16(const void* g, void* l) {
    __builtin_amdgcn_global_load_lds((const GLB unsigned int*)g,
                                     (LDS unsigned int*)l, 16, 0, 0);
}

__device__ __forceinline__ float read_sigma(const int* p) {
    int v = *p;
    if (v >= 1 && v < (1 << 20)) return (float)v;   // stored as int
    return __int_as_float(v);                        // stored as float bits
}

// ---- prep: convert 512-col f32 rows to bf16 + row sum of squares (4 rows/block) ----
__global__ __launch_bounds__(256) void prep_rows(const float* __restrict__ in,
                                                 unsigned short* __restrict__ outb,
                                                 float* __restrict__ out2) {
    int row  = blockIdx.x * 4 + (threadIdx.x >> 6);
    int lane = threadIdx.x & 63;
    const float4* p = (const float4*)(in + (size_t)row * D_DIM) + lane * 2;
    float4 a = p[0], b = p[1];
    float s = a.x*a.x + a.y*a.y + a.z*a.z + a.w*a.w
            + b.x*b.x + b.y*b.y + b.z*b.z + b.w*b.w;
    u16x8 o = { f2bf(a.x), f2bf(a.y), f2bf(a.z), f2bf(a.w),
                f2bf(b.x), f2bf(b.y), f2bf(b.z), f2bf(b.w) };
    *(u16x8*)(outb + (size_t)row * D_DIM + lane * 8) = o;
#pragma unroll
    for (int off = 32; off; off >>= 1) s += __shfl_down(s, off, 64);
    if (lane == 0) out2[row] = s;
}

// ---- prep: plain f32 -> bf16 convert (8 elems/thread) ----
__global__ __launch_bounds__(256) void conv_bf16(const float* __restrict__ in,
                                                 unsigned short* __restrict__ outb,
                                                 int n8) {
    int i = blockIdx.x * 256 + threadIdx.x;
    if (i >= n8) return;
    const float4* p = (const float4*)in + (size_t)i * 2;
    float4 a = p[0], b = p[1];
    u16x8 o = { f2bf(a.x), f2bf(a.y), f2bf(a.z), f2bf(a.w),
                f2bf(b.x), f2bf(b.y), f2bf(b.z), f2bf(b.w) };
    *((u16x8*)outb + i) = o;
}

// ---- stage a 128x64 bf16 half-tile (512 threads, 2 gload_lds each) ----
// linear LDS dest; inverse swizzle on SOURCE; read-side chunk swizzle c^(r&7)
__device__ __forceinline__ void stage_half(const unsigned short* __restrict__ g,
                                           int ld, int rowBase, int k0,
                                           unsigned short* lds, int tid) {
#pragma unroll
    for (int i = 0; i < 2; i++) {
        int idx = i * 512 + tid;          // 16B-chunk index, 0..1023
        int row = idx >> 3;               // 8 chunks per 64-elem row
        int cc  = (idx & 7) ^ (row & 7);  // inverse swizzle on SOURCE
        const unsigned short* src = g + (size_t)(rowBase + row) * ld + k0 + cc * 8;
        unsigned short* dst = lds + (i * 512 + (tid & 448)) * 8; // wave-uniform base
        async16(src, dst);
    }
}

__device__ __forceinline__ bf16x8 frag(const unsigned short* T, int r, int kc) {
    return *(const bf16x8*)(T + r * 64 + ((kc ^ (r & 7)) << 3));
}

// ---- one K-tile (BK=64): 4 phases, 16 MFMA each (kk-outer, dep distance 8);
//      stages K-tile t+2 into the same buffers (phase-disjoint regions) ----
__device__ __forceinline__ void ktile(unsigned short* __restrict__ Ap,
                                      unsigned short* __restrict__ Bp,
                                      const unsigned short* __restrict__ gA, int lda, int aRow0,
                                      const unsigned short* __restrict__ gB, int ldb, int bRow0,
                                      int kNext, bool doStage,
                                      f32x4 (&acc)[8][4], int tid, int l, int AR, int BC) {
    const int lr = l & 15, hi = l >> 4;
    bf16x8 a[4][2], b0[2][2], b1[2][2];

    // ---- PH0: ds_read A m0-3 + B n0-1 (12 reads); MFMA m0-3 x n0-1 ----
#pragma unroll
    for (int m = 0; m < 4; m++) { int r = AR + m * 16 + lr;
#pragma unroll
        for (int kk = 0; kk < 2; kk++) a[m][kk] = frag(Ap, r, kk * 4 + hi); }
#pragma unroll
    for (int n = 0; n < 2; n++) { int r = BC + n * 16 + lr;
#pragma unroll
        for (int kk = 0; kk < 2; kk++) b0[n][kk] = frag(Bp, r, kk * 4 + hi); }
    __builtin_amdgcn_s_barrier();
    LGKM0();
    __builtin_amdgcn_s_setprio(1);
#pragma unroll
    for (int kk = 0; kk < 2; kk++)
#pragma unroll
        for (int m = 0; m < 4; m++)
#pragma unroll
            for (int n = 0; n < 2; n++) MFMA(acc[m][n], a[m][kk], b0[n][kk]);
    __builtin_amdgcn_s_setprio(0);
    __builtin_amdgcn_s_barrier();

    // ---- PH1: ds_read B n2-3 (4 reads); MFMA m0-3 x n2-3 ----
#pragma unroll
    for (int n = 0; n < 2; n++) { int r = BC + (n + 2) * 16 + lr;
#pragma unroll
        for (int kk = 0; kk < 2; kk++) b1[n][kk] = frag(Bp, r, kk * 4 + hi); }
    __builtin_amdgcn_s_barrier();
    LGKM0();
    __builtin_amdgcn_s_setprio(1);
#pragma unroll
    for (int kk = 0; kk < 2; kk++)
#pragma unroll
        for (int m = 0; m < 4; m++)
#pragma unroll
            for (int n = 0; n < 2; n++) MFMA(acc[m][2 + n], a[m][kk], b1[n][kk]);
    __builtin_amdgcn_s_setprio(0);
    __builtin_amdgcn_s_barrier();

    // ---- PH2: ds_read A m4-7 (8 reads); stage B halves of t+2; MFMA m4-7 x n0-1 ----
#pragma unroll
    for (int m = 0; m < 4; m++) { int r = AR + (m + 4) * 16 + lr;
#pragma unroll
        for (int kk = 0; kk < 2; kk++) a[m][kk] = frag(Ap, r, kk * 4 + hi); }
    if (doStage) {
        stage_half(gB, ldb, bRow0,       kNext, Bp,        tid);
        stage_half(gB, ldb, bRow0 + 128, kNext, Bp + 8192, tid);
    }
    __builtin_amdgcn_s_barrier();
    LGKM0();
    __builtin_amdgcn_s_setprio(1);
#pragma unroll
    for (int kk = 0; kk < 2; kk++)
#pragma unroll
        for (int m = 0; m < 4; m++)
#pragma unroll
            for (int n = 0; n < 2; n++) MFMA(acc[4 + m][n], a[m][kk], b0[n][kk]);
    __builtin_amdgcn_s_setprio(0);
    __builtin_amdgcn_s_barrier();

    // ---- PH3: stage A halves of t+2; MFMA m4-7 x n2-3; boundary vmcnt(8) ----
    if (doStage) {
        stage_half(gA, lda, aRow0,       kNext, Ap,        tid);
        stage_half(gA, lda, aRow0 + 128, kNext, Ap + 8192, tid);
    }
    __builtin_amdgcn_s_barrier();
    __builtin_amdgcn_s_setprio(1);
#pragma unroll
    for (int kk = 0; kk < 2; kk++)
#pragma unroll
        for (int m = 0; m < 4; m++)
#pragma unroll
            for (int n = 0; n < 2; n++) MFMA(acc[4 + m][2 + n], a[m][kk], b1[n][kk]);
    __builtin_amdgcn_s_setprio(0);
    asm volatile("s_waitcnt vmcnt(8)" ::: "memory");   // keep t+2's 8 loads in flight
    __builtin_amdgcn_s_barrier();
}

__device__ __forceinline__ void gemm_core(const unsigned short* __restrict__ gA, int lda, int aRow0,
                                          const unsigned short* __restrict__ gB, int ldb, int bRow0,
                                          int nt, f32x4 (&acc)[8][4],
                                          unsigned short (&As)[2][16384],
                                          unsigned short (&Bs)[2][16384],
                                          int tid, int l, int AR, int BC) {
    // prologue: stage K-tiles 0 and 1 (order matters for vmcnt aging)
    stage_half(gA, lda, aRow0,       0,  As[0],        tid);
    stage_half(gA, lda, aRow0 + 128, 0,  As[0] + 8192, tid);
    stage_half(gB, ldb, bRow0,       0,  Bs[0],        tid);
    stage_half(gB, ldb, bRow0 + 128, 0,  Bs[0] + 8192, tid);
    stage_half(gA, lda, aRow0,       64, As[1],        tid);
    stage_half(gA, lda, aRow0 + 128, 64, As[1] + 8192, tid);
    stage_half(gB, ldb, bRow0,       64, Bs[1],        tid);
    stage_half(gB, ldb, bRow0 + 128, 64, Bs[1] + 8192, tid);
    asm volatile("s_waitcnt vmcnt(8)" ::: "memory");   // tile0 landed; tile1 in flight
    __builtin_amdgcn_s_barrier();

    for (int t = 0; t < nt; t += 2) {
        ktile(As[0], Bs[0], gA, lda, aRow0, gB, ldb, bRow0, (t + 2) * 64, t + 2 < nt,
              acc, tid, l, AR, BC);
        ktile(As[1], Bs[1], gA, lda, aRow0, gB, ldb, bRow0, (t + 3) * 64, t + 3 < nt,
              acc, tid, l, AR, BC);
    }
}

// ---- GEMM1: xc = x @ centers^T ; epilogue -> phi bf16 ----
__global__ __launch_bounds__(512) void gemm1_kernel(const unsigned short* __restrict__ xb,
                                                    const unsigned short* __restrict__ cb,
                                                    const float* __restrict__ x2,
                                                    const float* __restrict__ c2,
                                                    const int* __restrict__ sigp,
                                                    unsigned short* __restrict__ phi) {
    __shared__ unsigned short As[2][16384];
    __shared__ unsigned short Bs[2][16384];
    int tid = threadIdx.x;
    // XCD-chunked swizzle (nwg = 1024, %8 == 0)
    int nwg = gridDim.x, cpx = nwg >> 3, bid = blockIdx.x;
    int nb = (bid & 7) * cpx + (bid >> 3);
    const int nbx = C_DIM / 256;
    int aRow0 = (nb / nbx) * 256, bRow0 = (nb % nbx) * 256;
    int l = tid & 63, wid = tid >> 6;
    int AR = (wid >> 2) * 128, BC = (wid & 3) * 64;

    f32x4 acc[8][4] = {};
    gemm_core(xb, D_DIM, aRow0, cb, D_DIM, bRow0, D_DIM / 64, acc, As, Bs, tid, l, AR, BC);

    float inv2s = 0.5f / read_sigma(sigp);
    int lr = l & 15, hi = l >> 4;
#pragma unroll
    for (int m = 0; m < 8; m++) {
#pragma unroll
        for (int j = 0; j < 4; j++) {
            int row = aRow0 + AR + m * 16 + hi * 4 + j;
            float xr = x2[row];
#pragma unroll
            for (int n = 0; n < 4; n++) {
                int col = bRow0 + BC + n * 16 + lr;
                float d2 = fmaxf(xr + c2[col] - 2.0f * acc[m][n][j], 0.0f);
                float ph = __expf(-__builtin_sqrtf(d2) * inv2s);
                phi[(size_t)row * C_DIM + col] = f2bf(ph);
            }
        }
    }
}

// ---- GEMM2: out = sigmoid(phi @ W1^T + b1) ----
__global__ __launch_bounds__(512) void gemm2_kernel(const unsigned short* __restrict__ phi,
                                                    const unsigned short* __restrict__ wb,
                                                    const float* __restrict__ b1,
                                                    float* __restrict__ out) {
    __shared__ unsigned short As[2][16384];
    __shared__ unsigned short Bs[2][16384];
    int tid = threadIdx.x;
    // XCD-chunked swizzle (nwg = 256, %8 == 0)
    int nwg = gridDim.x, cpx = nwg >> 3, bid = blockIdx.x;
    int nb = (bid & 7) * cpx + (bid >> 3);
    const int nbx = H_DIM / 256;
    int aRow0 = (nb / nbx) * 256, bRow0 = (nb % nbx) * 256;
    int l = tid & 63, wid = tid >> 6;
    int AR = (wid >> 2) * 128, BC = (wid & 3) * 64;

    f32x4 acc[8][4] = {};
    gemm_core(phi, C_DIM, aRow0, wb, C_DIM, bRow0, C_DIM / 64, acc, As, Bs, tid, l, AR, BC);

    int lr = l & 15, hi = l >> 4;
#pragma unroll
    for (int m = 0; m < 8; m++) {
#pragma unroll
        for (int j = 0; j < 4; j++) {
            int row = aRow0 + AR + m * 16 + hi * 4 + j;
#pragma unroll
            for (int n = 0; n < 4; n++) {
                int col = bRow0 + BC + n * 16 + lr;
                float z = acc[m][n][j] + b1[col];
                out[(size_t)row * H_DIM + col] = 1.0f / (1.0f + __expf(-z));
            }
        }
    }
}

extern "C" void kernel_launch(void* const* d_in, const int* in_sizes, int n_in,
                              void* d_out, int out_size, void* d_ws, size_t ws_size,
                              hipStream_t stream) {
    const float* x       = (const float*)d_in[0];
    const float* centers = (const float*)d_in[1];
    const float* W1      = (const float*)d_in[2];
    const float* b1      = (const float*)d_in[3];
    const int*   sig     = (const int*)d_in[4];
    float* out = (float*)d_out;

    char* ws = (char*)d_ws;
    unsigned short* phi = (unsigned short*)(ws);                 // 16384*4096*2 = 134217728
    unsigned short* xb  = (unsigned short*)(ws + 134217728);     // 16384*512*2  = 16777216
    unsigned short* cb  = (unsigned short*)(ws + 150994944);     // 4096*512*2   = 4194304
    unsigned short* wb  = (unsigned short*)(ws + 155189248);     // 1024*4096*2  = 8388608
    float* x2 = (float*)(ws + 163577856);                        // 16384*4
    float* c2 = (float*)(ws + 163643392);                        // 4096*4

    prep_rows<<<B_ROWS / 4, 256, 0, stream>>>(x, xb, x2);
    prep_rows<<<C_DIM / 4, 256, 0, stream>>>(centers, cb, c2);
    conv_bf16<<<(H_DIM * C_DIM / 8 + 255) / 256, 256, 0, stream>>>(W1, wb, H_DIM * C_DIM / 8);

    gemm1_kernel<<<(B_ROWS / 256) * (C_DIM / 256), 512, 0, stream>>>(xb, cb, x2, c2, sig, phi);
    gemm2_kernel<<<(B_ROWS / 256) * (H_DIM / 256), 512, 0, stream>>>(phi, wb, b1, out);
}